// Round 1
// 1753.377 us; speedup vs baseline: 1.0427x; 1.0427x over previous
//
#include <hip/hip_runtime.h>
#include <hip/hip_bf16.h>

#define D_MODEL 768
#define SEQ     1024
#define NB      8
#define NHEAD   12
#define HS      64
#define NLAYER  4
#define DFF     3072
#define NCLS    16
#define MROWS   (NB*SEQ)   // 8192

typedef float f32x4  __attribute__((ext_vector_type(4)));
typedef short bf16x8 __attribute__((ext_vector_type(8)));

__device__ __forceinline__ short f2bf_s(float x) {
    __hip_bfloat16 h = __float2bfloat16(x);
    union { __hip_bfloat16 h; short s; } u; u.h = h; return u.s;
}

// async global->LDS, 16B per lane; lds base must be wave-uniform (HW adds lane*16)
__device__ __forceinline__ void gld16(const void* g, void* l) {
    __builtin_amdgcn_global_load_lds((const __attribute__((address_space(1))) void*)g,
                                     (__attribute__((address_space(3))) void*)l, 16, 0, 0);
}

// ---------------------------------------------------------------- embedding
__global__ __launch_bounds__(256) void embed_kernel(
    const int* __restrict__ x, const float* __restrict__ tok,
    const float* __restrict__ pos, float* __restrict__ h)
{
    int row = blockIdx.x;
    int s   = row & (SEQ - 1);
    int t   = threadIdx.x;
    int id  = x[row];
    const float* te = tok + (size_t)id * D_MODEL;
    const float* pe = pos + (size_t)s  * D_MODEL;
    float* hr = h + (size_t)row * D_MODEL;
    for (int d = t; d < D_MODEL; d += 256) hr[d] = te[d] + pe[d];
}

// ---------------------------------------------------------------- layernorm
template<int BF16OUT>
__global__ __launch_bounds__(256) void ln_kernel(
    const float* __restrict__ in, const float* __restrict__ w,
    const float* __restrict__ b, void* __restrict__ outv,
    int row_stride, int row_offset)
{
    __shared__ float red[256];
    int r = blockIdx.x;
    const float* xr = in + (size_t)(r * row_stride + row_offset) * D_MODEL;
    int t = threadIdx.x;
    float v0 = xr[t], v1 = xr[t + 256], v2 = xr[t + 512];
    red[t] = v0 + v1 + v2; __syncthreads();
    for (int off = 128; off; off >>= 1) { if (t < off) red[t] += red[t + off]; __syncthreads(); }
    float mu = red[0] * (1.f / D_MODEL);
    __syncthreads();
    float d0 = v0 - mu, d1 = v1 - mu, d2 = v2 - mu;
    red[t] = d0*d0 + d1*d1 + d2*d2; __syncthreads();
    for (int off = 128; off; off >>= 1) { if (t < off) red[t] += red[t + off]; __syncthreads(); }
    float rstd = rsqrtf(red[0] * (1.f / D_MODEL) + 1e-5f);
    float y0 = d0 * rstd * w[t]       + b[t];
    float y1 = d1 * rstd * w[t + 256] + b[t + 256];
    float y2 = d2 * rstd * w[t + 512] + b[t + 512];
    if (BF16OUT) {
        __hip_bfloat16* yr = (__hip_bfloat16*)outv + (size_t)r * D_MODEL;
        yr[t] = __float2bfloat16(y0); yr[t+256] = __float2bfloat16(y1); yr[t+512] = __float2bfloat16(y2);
    } else {
        float* yr = (float*)outv + (size_t)r * D_MODEL;
        yr[t] = y0; yr[t+256] = y1; yr[t+512] = y2;
    }
}

// --------------------------------------------- weight convert+transpose to bf16
template<int MODE>
__global__ __launch_bounds__(256) void convw_kernel(
    const float* __restrict__ W, __hip_bfloat16* __restrict__ BT,
    int K, int N, size_t in_stride, size_t out_stride)
{
    __shared__ __hip_bfloat16 sT[64][72];
    W  += (size_t)blockIdx.z * in_stride;
    BT += (size_t)blockIdx.z * out_stride;
    int k0 = blockIdx.x * 64, n0 = blockIdx.y * 64;
    int t = threadIdx.x;
    int kl = t >> 4, nl4 = (t & 15) * 4;
    #pragma unroll
    for (int i = 0; i < 4; i++) {
        int k = k0 + kl + i * 16;
        int n = n0 + nl4;
        const float* src = (MODE == 0) ? (W + (size_t)k * N + n)
                                       : (W + ((size_t)(n >> 6) * K + k) * 64 + (n & 63));
        float4 v = *(const float4*)src;
        sT[nl4 + 0][kl + i*16] = __float2bfloat16(v.x);
        sT[nl4 + 1][kl + i*16] = __float2bfloat16(v.y);
        sT[nl4 + 2][kl + i*16] = __float2bfloat16(v.z);
        sT[nl4 + 3][kl + i*16] = __float2bfloat16(v.w);
    }
    __syncthreads();
    int nl = t >> 2, seg = (t & 3) * 16;
    uint4* dst = (uint4*)(BT + (size_t)(n0 + nl) * K + k0 + seg);
    dst[0] = *(uint4*)&sT[nl][seg];
    dst[1] = *(uint4*)&sT[nl][seg + 8];
}

// ---------------------------------------------------------------- bf16 MFMA GEMM
// 2-phase prefetch double-buffer (T3 minimum): issue next tile's global_load_lds
// BEFORE compute, single vmcnt(0)+barrier per tile -> HBM latency hides under MFMA.
// OMODE: 0 = f32 out (+bias,+res)   1 = QKV bf16 scatter   2 = bf16 out
//        3 = split-K over blockIdx.z, atomicAdd f32 into C (C pre-holds residual;
//            bias added by z==0 slice only; relu unsupported)
template<int OMODE>
__global__ __launch_bounds__(256, 3) void gemm128(
    const __hip_bfloat16* __restrict__ A, const __hip_bfloat16* __restrict__ BT,
    const float* __restrict__ bias, const float* __restrict__ res,
    void* __restrict__ Cv, int M, int N, int K, int relu)
{
    __shared__ short sA[2][128 * 32];
    __shared__ short sB[2][128 * 32];
    int t = threadIdx.x;
    int wave = t >> 6, lane = t & 63;
    int l16 = lane & 15, quad = (lane >> 4) & 3;
    int wm = wave >> 1, wn = wave & 1;
    int bm = blockIdx.x * 128, bn = blockIdx.y * 128;

    int kbeg = 0, kend = K;
    if (OMODE == 3) { int KS = K >> 1; kbeg = blockIdx.z * KS; kend = kbeg + KS; }

    int u = lane >> 2;
    int skey = ((u & 3) ^ ((u >> 2) & 3));
    int sseg = (lane & 3) ^ skey;
    int c0 = wave * 2, c1 = wave * 2 + 1;
    int rA0 = c0 * 16 + u, rA1 = c1 * 16 + u;
    int fkey = ((l16 & 3) ^ ((l16 >> 2) & 3));

    const f32x4 zf = {0.f, 0.f, 0.f, 0.f};
    f32x4 acc[4][4];
    #pragma unroll
    for (int mi = 0; mi < 4; mi++)
        #pragma unroll
        for (int ni = 0; ni < 4; ni++) acc[mi][ni] = zf;

    #define STAGE(bufi, kk) do { \
        gld16(A  + (size_t)(bm + rA0) * K + (kk) + sseg * 8, &sA[bufi][c0 * 512]); \
        gld16(A  + (size_t)(bm + rA1) * K + (kk) + sseg * 8, &sA[bufi][c1 * 512]); \
        gld16(BT + (size_t)(bn + rA0) * K + (kk) + sseg * 8, &sB[bufi][c0 * 512]); \
        gld16(BT + (size_t)(bn + rA1) * K + (kk) + sseg * 8, &sB[bufi][c1 * 512]); \
    } while (0)

    STAGE(0, kbeg);
    __syncthreads();
    int buf = 0;
    for (int k0 = kbeg; k0 < kend; k0 += 32) {
        int kn = k0 + 32;
        if (kn < kend) STAGE(buf ^ 1, kn);     // prefetch next tile (in flight during MFMA)
        bf16x8 aF[4], bF[4];
        #pragma unroll
        for (int mi = 0; mi < 4; mi++)
            aF[mi] = *(bf16x8*)&sA[buf][(wm * 64 + mi * 16 + l16) * 32 + ((quad ^ fkey) * 8)];
        #pragma unroll
        for (int ni = 0; ni < 4; ni++)
            bF[ni] = *(bf16x8*)&sB[buf][(wn * 64 + ni * 16 + l16) * 32 + ((quad ^ fkey) * 8)];
        #pragma unroll
        for (int ni = 0; ni < 4; ni++)
            #pragma unroll
            for (int mi = 0; mi < 4; mi++)
                acc[mi][ni] = __builtin_amdgcn_mfma_f32_16x16x32_bf16(aF[mi], bF[ni], acc[mi][ni], 0, 0, 0);
        __syncthreads();                        // drains the prefetch; next buffer ready
        buf ^= 1;
    }
    #undef STAGE

    #pragma unroll
    for (int mi = 0; mi < 4; mi++) {
        #pragma unroll
        for (int ni = 0; ni < 4; ni++) {
            int row0 = bm + wm * 64 + mi * 16 + quad * 4;
            int col  = bn + wn * 64 + ni * 16 + l16;
            #pragma unroll
            for (int r = 0; r < 4; r++) {
                int row = row0 + r;
                float v = acc[mi][ni][r];
                if (OMODE == 3) {
                    float* C = (float*)Cv;
                    if (blockIdx.z == 0 && bias) v += bias[col];
                    unsafeAtomicAdd(&C[(size_t)row * N + col], v);
                    continue;
                }
                if (OMODE != 1 && bias) v += bias[col];
                if (relu) v = fmaxf(v, 0.f);
                if (OMODE == 0) {
                    float* C = (float*)Cv;
                    if (res) v += res[(size_t)row * N + col];
                    C[(size_t)row * N + col] = v;
                } else if (OMODE == 1) {
                    int which = col / D_MODEL, cc = col % D_MODEL;
                    int bb = row >> 10, ss = row & 1023, hh = cc >> 6, e = cc & 63;
                    ((__hip_bfloat16*)Cv)[(size_t)which * MROWS * D_MODEL +
                        (((size_t)(bb * NHEAD + hh)) * SEQ + ss) * HS + e] = __float2bfloat16(v);
                } else {
                    ((__hip_bfloat16*)Cv)[(size_t)row * N + col] = __float2bfloat16(v);
                }
            }
        }
    }
    (void)M;
}

// ---------------------------------------------------------------- V transpose: (bh,s,e) -> (bh,e,s)
__global__ __launch_bounds__(256) void vtrans_kernel(
    const __hip_bfloat16* __restrict__ vb, __hip_bfloat16* __restrict__ vt)
{
    __shared__ short tile[64][66];
    int bh = blockIdx.x, st = blockIdx.y;
    const short* src = (const short*)vb + ((size_t)bh * SEQ + st * 64) * HS;
    int t = threadIdx.x;
    #pragma unroll
    for (int i = 0; i < 2; i++) {
        int slot = t + i * 256;
        int row = slot >> 3, seg = slot & 7;
        *(uint4*)&tile[row][seg * 8] = *(const uint4*)(src + row * HS + seg * 8);
    }
    __syncthreads();
    short* dst = (short*)vt + (size_t)bh * HS * SEQ + st * 64;
    #pragma unroll
    for (int i = 0; i < 2; i++) {
        int slot = t + i * 256;
        int e = slot >> 3, seg = slot & 7;
        union { uint4 u; short s[8]; } pk;
        #pragma unroll
        for (int j = 0; j < 8; j++) pk.s[j] = tile[seg * 8 + j][e];
        *(uint4*)(dst + (size_t)e * SEQ + seg * 8) = pk.u;
    }
}

// ---------------------------------------------------------------- MFMA flash attention v3 (S^T orientation)
// Block = 2 waves = 128 queries of one (b,h); wave owns 64 queries (4 qt-tiles).
// CHANGES vs prev: (1) XCD-bijective blockIdx remap so the 8 q-blocks of one (b,h)
// land on ONE XCD -> K/VT are L2-local instead of 8x HBM-refetched.
// (2) double-buffered sK/sVT with prefetch-before-compute: one vmcnt(0)+barrier per
// K-tile, issued AFTER ~1500cy of MFMA/softmax has hidden the load latency.
__global__ __launch_bounds__(128, 2) void attn_mfma_kernel(
    const __hip_bfloat16* __restrict__ q, const __hip_bfloat16* __restrict__ k,
    const __hip_bfloat16* __restrict__ v, const int* __restrict__ mask,
    __hip_bfloat16* __restrict__ ao)
{
    __shared__ short sK[2][64 * 64];
    __shared__ short sVT[2][64 * 64];
    __shared__ short sP[2][64 * 64];
    __shared__ float mskf[SEQ];
    // XCD remap: dispatch round-robins blockIdx%8 across XCDs. Map so all 8 blocks
    // sharing a bh have the same (blockIdx%8). Bijective on [0,768).
    int bid = blockIdx.x;
    int xcd = bid & 7, j = bid >> 3;
    int bh  = ((j >> 3) << 3) | xcd;
    int qt8 = j & 7;
    int b = bh / NHEAD, hh = bh % NHEAD;
    int t = threadIdx.x, w = t >> 6, lane = t & 63;
    int l16 = lane & 15, quad = lane >> 4;
    const float scale = 0.036084391824351615f;  // 768^-0.5
    const f32x4 zf = {0.f, 0.f, 0.f, 0.f};

    #pragma unroll
    for (int i = 0; i < 8; i++) {
        int idx = t + i * 128;
        mskf[idx] = mask[b * SEQ + idx] ? 0.f : -1e30f;
    }

    // Q B-frags: lane n=query(l16), k=dim s*32+quad*8..+7
    int qb0 = qt8 * 128 + w * 64;
    const __hip_bfloat16* qbase = q + ((size_t)bh * SEQ + qb0) * HS;
    bf16x8 qf[4][2];
    #pragma unroll
    for (int qt = 0; qt < 4; qt++)
        #pragma unroll
        for (int s = 0; s < 2; s++)
            qf[qt][s] = *(const bf16x8*)(qbase + (qt * 16 + l16) * HS + s * 32 + quad * 8);

    f32x4 accO[4][4];            // [dt][qt]: O^T tile, row=dim dt*16+quad*4+r, col=query qt*16+l16
    float m_st[4], l_st[4];      // per qt (query qt*16+l16)
    #pragma unroll
    for (int dt = 0; dt < 4; dt++)
        #pragma unroll
        for (int qt = 0; qt < 4; qt++) accO[dt][qt] = zf;
    #pragma unroll
    for (int qt = 0; qt < 4; qt++) { m_st[qt] = -1e30f; l_st[qt] = 0.f; }

    // staging geometry
    int rowL = lane >> 3;
    int sgl = ((lane & 7) ^ ((lane >> 3) & 7)) * 8;   // swizzled global seg (shorts)
    const __hip_bfloat16* kg0 = k + ((size_t)bh * SEQ) * HS;
    const __hip_bfloat16* vtg0 = v + (size_t)bh * HS * SEQ;   // v = pre-transposed vT here
    short* myP = &sP[w][0];

    // prologue: stage K-tile 0 into buffer 0
    #pragma unroll
    for (int i = 0; i < 4; i++) {
        int c = w * 4 + i;
        int rr = c * 8 + rowL;
        gld16(kg0  + (size_t)rr * HS  + sgl, (char*)&sK[0][0]  + c * 1024);
        gld16(vtg0 + (size_t)rr * SEQ + sgl, (char*)&sVT[0][0] + c * 1024);
    }
    __syncthreads();

    int buf = 0;
    for (int kc = 0; kc < 16; kc++) {
        // prefetch next K-tile into the other buffer (in flight during compute)
        if (kc < 15) {
            const __hip_bfloat16* kg  = kg0  + (size_t)(kc + 1) * 64 * HS;
            const __hip_bfloat16* vtg = vtg0 + (kc + 1) * 64;
            #pragma unroll
            for (int i = 0; i < 4; i++) {
                int c = w * 4 + i;
                int rr = c * 8 + rowL;
                gld16(kg  + (size_t)rr * HS  + sgl, (char*)&sK[buf ^ 1][0]  + c * 1024);
                gld16(vtg + (size_t)rr * SEQ + sgl, (char*)&sVT[buf ^ 1][0] + c * 1024);
            }
        }
        short* cK  = &sK[buf][0];
        short* cVT = &sVT[buf][0];

        // all sK/sVT reads up front
        bf16x8 vf[4][2];
        #pragma unroll
        for (int dt = 0; dt < 4; dt++)
            #pragma unroll
            for (int s = 0; s < 2; s++)
                vf[dt][s] = *(bf16x8*)&cVT[(dt * 16 + l16) * 64 + (((s * 4 + quad) ^ (l16 & 7)) * 8)];
        f32x4 sc[4][4];   // [kt][qt]
        #pragma unroll
        for (int kt = 0; kt < 4; kt++) {
            bf16x8 kf0 = *(bf16x8*)&cK[(kt * 16 + l16) * 64 + ((quad ^ (l16 & 7)) * 8)];
            bf16x8 kf1 = *(bf16x8*)&cK[(kt * 16 + l16) * 64 + (((4 + quad) ^ (l16 & 7)) * 8)];
            #pragma unroll
            for (int qt = 0; qt < 4; qt++) {
                f32x4 c = __builtin_amdgcn_mfma_f32_16x16x32_bf16(kf0, qf[qt][0], zf, 0, 0, 0);
                sc[kt][qt] = __builtin_amdgcn_mfma_f32_16x16x32_bf16(kf1, qf[qt][1], c, 0, 0, 0);
            }
        }
        // scale + mask (mask indexed by key row)
        #pragma unroll
        for (int kt = 0; kt < 4; kt++) {
            f32x4 mk = *(f32x4*)&mskf[kc * 64 + kt * 16 + quad * 4];
            #pragma unroll
            for (int qt = 0; qt < 4; qt++)
                #pragma unroll
                for (int r = 0; r < 4; r++)
                    sc[kt][qt][r] = sc[kt][qt][r] * scale + mk[r];
        }
        // online softmax per query column
        #pragma unroll
        for (int qt = 0; qt < 4; qt++) {
            float rm = -1e30f;
            #pragma unroll
            for (int kt = 0; kt < 4; kt++)
                #pragma unroll
                for (int r = 0; r < 4; r++) rm = fmaxf(rm, sc[kt][qt][r]);
            rm = fmaxf(rm, __shfl_xor(rm, 16));
            rm = fmaxf(rm, __shfl_xor(rm, 32));
            float mnew = fmaxf(m_st[qt], rm);
            float corr = __expf(m_st[qt] - mnew);
            m_st[qt] = mnew;
            float ps = 0.f;
            #pragma unroll
            for (int kt = 0; kt < 4; kt++) {
                union { uint2 u; short s[4]; } pk;
                #pragma unroll
                for (int r = 0; r < 4; r++) {
                    float p = __expf(sc[kt][qt][r] - mnew);
                    ps += p;
                    pk.s[r] = f2bf_s(p);
                }
                // P[query][key], keys kt*16+quad*4..+3; seg swizzle on query row bits
                *(uint2*)&myP[(qt * 16 + l16) * 64 +
                              (((kt * 2 + (quad >> 1)) ^ (l16 & 7)) * 8) + (quad & 1) * 4] = pk.u;
            }
            ps += __shfl_xor(ps, 16);
            ps += __shfl_xor(ps, 32);
            l_st[qt] = l_st[qt] * corr + ps;
            #pragma unroll
            for (int dt = 0; dt < 4; dt++) accO[dt][qt] *= corr;
        }
        asm volatile("" ::: "memory");   // keep pf reads after P writes (same-wave DS is in-order)
        // PV: O^T += V^T @ P^T  (B-frag = P rows)
        #pragma unroll
        for (int qt = 0; qt < 4; qt++) {
            bf16x8 pf0 = *(bf16x8*)&myP[(qt * 16 + l16) * 64 + ((quad ^ (l16 & 7)) * 8)];
            bf16x8 pf1 = *(bf16x8*)&myP[(qt * 16 + l16) * 64 + (((4 + quad) ^ (l16 & 7)) * 8)];
            #pragma unroll
            for (int dt = 0; dt < 4; dt++) {
                accO[dt][qt] = __builtin_amdgcn_mfma_f32_16x16x32_bf16(vf[dt][0], pf0, accO[dt][qt], 0, 0, 0);
                accO[dt][qt] = __builtin_amdgcn_mfma_f32_16x16x32_bf16(vf[dt][1], pf1, accO[dt][qt], 0, 0, 0);
            }
        }
        __syncthreads();   // drains prefetch (had full compute phase to land); next buffer ready
        buf ^= 1;
    }

    // epilogue: O = O^T / l, pack 4 consecutive dims per b64 store
    #pragma unroll
    for (int qt = 0; qt < 4; qt++) {
        float inv = 1.f / l_st[qt];
        int row = qb0 + qt * 16 + l16;
        __hip_bfloat16* orow = ao + ((size_t)(b * SEQ + row)) * D_MODEL + hh * HS;
        #pragma unroll
        for (int dt = 0; dt < 4; dt++) {
            union { uint2 u; short s[4]; } pk;
            #pragma unroll
            for (int r = 0; r < 4; r++) pk.s[r] = f2bf_s(accO[dt][qt][r] * inv);
            *(uint2*)(orow + dt * 16 + quad * 4) = pk.u;
        }
    }
}

// ---------------------------------------------------------------- head FC1: (8,768)@(768,3072)+relu
__global__ __launch_bounds__(256) void fc1_kernel(
    const float* __restrict__ A, const float* __restrict__ W,
    const float* __restrict__ bias, float* __restrict__ out)
{
    __shared__ float sa[D_MODEL];
    int row = blockIdx.x, t = threadIdx.x;
    for (int i = t; i < D_MODEL; i += 256) sa[i] = A[(size_t)row * D_MODEL + i];
    __syncthreads();
    int col = blockIdx.y * 256 + t;
    float s = 0.f;
    #pragma unroll 8
    for (int kk = 0; kk < D_MODEL; kk++) s = fmaf(sa[kk], W[(size_t)kk * DFF + col], s);
    s += bias[col];
    out[(size_t)row * DFF + col] = fmaxf(s, 0.f);
}

// ---------------------------------------------------------------- head FC2: (8,3072)@(3072,16)
__global__ __launch_bounds__(256) void fc2_kernel(
    const float* __restrict__ A, const float* __restrict__ W,
    const float* __restrict__ bias, float* __restrict__ out)
{
    __shared__ float wred[4][NCLS];
    int row = blockIdx.x, t = threadIdx.x;
    int wave = t >> 6, lane = t & 63;
    const float* a = A + (size_t)row * DFF;
    float acc[NCLS];
    #pragma unroll
    for (int c = 0; c < NCLS; c++) acc[c] = 0.f;
    for (int kk = t; kk < DFF; kk += 256) {
        float av = a[kk];
        const float4* wr = (const float4*)(W + (size_t)kk * NCLS);
        float4 w0 = wr[0], w1 = wr[1], w2 = wr[2], w3 = wr[3];
        acc[0]  = fmaf(av, w0.x, acc[0]);  acc[1]  = fmaf(av, w0.y, acc[1]);
        acc[2]  = fmaf(av, w0.z, acc[2]);  acc[3]  = fmaf(av, w0.w, acc[3]);
        acc[4]  = fmaf(av, w1.x, acc[4]);  acc[5]  = fmaf(av, w1.y, acc[5]);
        acc[6]  = fmaf(av, w1.z, acc[6]);  acc[7]  = fmaf(av, w1.w, acc[7]);
        acc[8]  = fmaf(av, w2.x, acc[8]);  acc[9]  = fmaf(av, w2.y, acc[9]);
        acc[10] = fmaf(av, w2.z, acc[10]); acc[11] = fmaf(av, w2.w, acc[11]);
        acc[12] = fmaf(av, w3.x, acc[12]); acc[13] = fmaf(av, w3.y, acc[13]);
        acc[14] = fmaf(av, w3.z, acc[14]); acc[15] = fmaf(av, w3.w, acc[15]);
    }
    #pragma unroll
    for (int c = 0; c < NCLS; c++)
        #pragma unroll
        for (int off = 32; off; off >>= 1) acc[c] += __shfl_down(acc[c], off);
    if (lane == 0)
        #pragma unroll
        for (int c = 0; c < NCLS; c++) wred[wave][c] = acc[c];
    __syncthreads();
    if (t < NCLS)
        out[row * NCLS + t] = wred[0][t] + wred[1][t] + wred[2][t] + wred[3][t] + bias[t];
}

// ---------------------------------------------------------------- launch
extern "C" void kernel_launch(void* const* d_in, const int* in_sizes, int n_in,
                              void* d_out, int out_size, void* d_ws, size_t ws_size,
                              hipStream_t stream)
{
    const int*   x     = (const int*)  d_in[0];
    const int*   amask = (const int*)  d_in[1];
    const float* tok   = (const float*)d_in[2];
    const float* pos   = (const float*)d_in[3];
    const float* Wq    = (const float*)d_in[4];
    const float* Wk    = (const float*)d_in[5];
    const float* Wv    = (const float*)d_in[6];
    const float* Wo    = (const float*)d_in[7];
    const float* bo    = (const float*)d_in[8];
    const float* ln1w  = (const float*)d_in[9];
    const float* ln1b  = (const float*)d_in[10];
    const float* ln2w  = (const float*)d_in[11];
    const float* ln2b  = (const float*)d_in[12];
    const float* W1    = (const float*)d_in[13];
    const float* b1    = (const float*)d_in[14];
    const float* W2    = (const float*)d_in[15];
    const float* b2    = (const float*)d_in[16];
    const float* lnfw  = (const float*)d_in[17];
    const float* lnfb  = (const float*)d_in[18];
    const float* cW1   = (const float*)d_in[19];
    const float* cb1   = (const float*)d_in[20];
    const float* cW2   = (const float*)d_in[21];
    const float* cb2   = (const float*)d_in[22];

    char* base = (char*)d_ws;
    const size_t MD = (size_t)MROWS * D_MODEL;
    float* h = (float*)base;                         base += MD * 4;
    __hip_bfloat16* xn = (__hip_bfloat16*)base;      base += MD * 2;
    __hip_bfloat16* qb = (__hip_bfloat16*)base;      base += MD * 2;
    __hip_bfloat16* kb = (__hip_bfloat16*)base;      base += MD * 2;
    __hip_bfloat16* vb = (__hip_bfloat16*)base;      base += MD * 2;
    __hip_bfloat16* vT = (__hip_bfloat16*)base;      base += MD * 2;
    __hip_bfloat16* ff = (__hip_bfloat16*)base;      base += (size_t)MROWS * DFF * 2;
    float* lnf = (float*)base;                       base += (size_t)NB * D_MODEL * 4;
    float* cls = (float*)base;                       base += (size_t)NB * DFF * 4;
    __hip_bfloat16* wQKV = (__hip_bfloat16*)base;    base += (size_t)NLAYER * 3 * D_MODEL * D_MODEL * 2;
    __hip_bfloat16* wTo = (__hip_bfloat16*)base;     base += (size_t)NLAYER * D_MODEL * D_MODEL * 2;
    __hip_bfloat16* wT1 = (__hip_bfloat16*)base;     base += (size_t)NLAYER * D_MODEL * DFF * 2;
    __hip_bfloat16* wT2 = (__hip_bfloat16*)base;     base += (size_t)NLAYER * DFF * D_MODEL * 2;

    const size_t SQW = (size_t)D_MODEL * D_MODEL;
    const size_t SFF = (size_t)D_MODEL * DFF;

    convw_kernel<1><<<dim3(12,12,4), 256, 0, stream>>>(Wq, wQKV + 0 * SQW, D_MODEL, D_MODEL, SQW, 3 * SQW);
    convw_kernel<1><<<dim3(12,12,4), 256, 0, stream>>>(Wk, wQKV + 1 * SQW, D_MODEL, D_MODEL, SQW, 3 * SQW);
    convw_kernel<1><<<dim3(12,12,4), 256, 0, stream>>>(Wv, wQKV + 2 * SQW, D_MODEL, D_MODEL, SQW, 3 * SQW);
    convw_kernel<0><<<dim3(12,12,4), 256, 0, stream>>>(Wo, wTo, D_MODEL, D_MODEL, SQW, SQW);
    convw_kernel<0><<<dim3(12,48,4), 256, 0, stream>>>(W1, wT1, D_MODEL, DFF, SFF, SFF);
    convw_kernel<0><<<dim3(48,12,4), 256, 0, stream>>>(W2, wT2, DFF, D_MODEL, SFF, SFF);

    embed_kernel<<<MROWS, 256, 0, stream>>>(x, tok, pos, h);

    dim3 gQKV(MROWS / 128, (3 * D_MODEL) / 128);
    dim3 gDS(MROWS / 128, D_MODEL / 128, 2);   // split-K=2
    dim3 gF(MROWS / 128, DFF / 128);
    for (int l = 0; l < NLAYER; l++) {
        ln_kernel<1><<<MROWS, 256, 0, stream>>>(h, ln1w + l * D_MODEL, ln1b + l * D_MODEL, xn, 1, 0);
        gemm128<1><<<gQKV, 256, 0, stream>>>(xn, wQKV + l * 3 * SQW, nullptr, nullptr, qb, MROWS, 3 * D_MODEL, D_MODEL, 0);
        vtrans_kernel<<<dim3(NB * NHEAD, SEQ / 64), 256, 0, stream>>>(vb, vT);
        attn_mfma_kernel<<<NB * NHEAD * 8, 128, 0, stream>>>(qb, kb, vT, amask, xn);
        gemm128<3><<<gDS, 256, 0, stream>>>(xn, wTo + l * SQW, bo + l * D_MODEL, nullptr, h, MROWS, D_MODEL, D_MODEL, 0);
        ln_kernel<1><<<MROWS, 256, 0, stream>>>(h, ln2w + l * D_MODEL, ln2b + l * D_MODEL, xn, 1, 0);
        gemm128<2><<<gF, 256, 0, stream>>>(xn, wT1 + l * SFF, b1 + l * DFF, nullptr, ff, MROWS, DFF, D_MODEL, 1);
        gemm128<3><<<gDS, 256, 0, stream>>>(ff, wT2 + l * SFF, b2 + l * D_MODEL, nullptr, h, MROWS, D_MODEL, DFF, 0);
    }
    ln_kernel<0><<<NB, 256, 0, stream>>>(h, lnfw, lnfb, lnf, SEQ, SEQ - 1);
    fc1_kernel<<<dim3(NB, DFF / 256), 256, 0, stream>>>(lnf, cW1, cb1, cls);
    fc2_kernel<<<NB, 256, 0, stream>>>(cls, cW2, cb2, (float*)d_out);
}

// Round 2
// 1674.513 us; speedup vs baseline: 1.0918x; 1.0471x over previous
//
#include <hip/hip_runtime.h>
#include <hip/hip_bf16.h>

#define D_MODEL 768
#define SEQ     1024
#define NB      8
#define NHEAD   12
#define HS      64
#define NLAYER  4
#define DFF     3072
#define NCLS    16
#define MROWS   (NB*SEQ)   // 8192

typedef float f32x4  __attribute__((ext_vector_type(4)));
typedef short bf16x8 __attribute__((ext_vector_type(8)));

__device__ __forceinline__ short f2bf_s(float x) {
    __hip_bfloat16 h = __float2bfloat16(x);
    union { __hip_bfloat16 h; short s; } u; u.h = h; return u.s;
}

// async global->LDS, 16B per lane; lds base must be wave-uniform (HW adds lane*16)
__device__ __forceinline__ void gld16(const void* g, void* l) {
    __builtin_amdgcn_global_load_lds((const __attribute__((address_space(1))) void*)g,
                                     (__attribute__((address_space(3))) void*)l, 16, 0, 0);
}

// ---------------------------------------------------------------- embedding
__global__ __launch_bounds__(256) void embed_kernel(
    const int* __restrict__ x, const float* __restrict__ tok,
    const float* __restrict__ pos, float* __restrict__ h)
{
    int row = blockIdx.x;
    int s   = row & (SEQ - 1);
    int t   = threadIdx.x;
    int id  = x[row];
    const float* te = tok + (size_t)id * D_MODEL;
    const float* pe = pos + (size_t)s  * D_MODEL;
    float* hr = h + (size_t)row * D_MODEL;
    for (int d = t; d < D_MODEL; d += 256) hr[d] = te[d] + pe[d];
}

// ---------------------------------------------------------------- layernorm
// wave shuffle-reduce + 4-slot LDS combine: 2 barriers instead of 16
template<int BF16OUT>
__global__ __launch_bounds__(256) void ln_kernel(
    const float* __restrict__ in, const float* __restrict__ w,
    const float* __restrict__ b, void* __restrict__ outv,
    int row_stride, int row_offset)
{
    __shared__ float part[8];
    int r = blockIdx.x;
    const float* xr = in + (size_t)(r * row_stride + row_offset) * D_MODEL;
    int t = threadIdx.x, wave = t >> 6, lane = t & 63;
    float v0 = xr[t], v1 = xr[t + 256], v2 = xr[t + 512];
    float s = v0 + v1 + v2;
    #pragma unroll
    for (int off = 32; off; off >>= 1) s += __shfl_xor(s, off);
    if (lane == 0) part[wave] = s;
    __syncthreads();
    float mu = (part[0] + part[1] + part[2] + part[3]) * (1.f / D_MODEL);
    float d0 = v0 - mu, d1 = v1 - mu, d2 = v2 - mu;
    float q = d0*d0 + d1*d1 + d2*d2;
    #pragma unroll
    for (int off = 32; off; off >>= 1) q += __shfl_xor(q, off);
    if (lane == 0) part[4 + wave] = q;
    __syncthreads();
    float rstd = rsqrtf((part[4] + part[5] + part[6] + part[7]) * (1.f / D_MODEL) + 1e-5f);
    float y0 = d0 * rstd * w[t]       + b[t];
    float y1 = d1 * rstd * w[t + 256] + b[t + 256];
    float y2 = d2 * rstd * w[t + 512] + b[t + 512];
    if (BF16OUT) {
        __hip_bfloat16* yr = (__hip_bfloat16*)outv + (size_t)r * D_MODEL;
        yr[t] = __float2bfloat16(y0); yr[t+256] = __float2bfloat16(y1); yr[t+512] = __float2bfloat16(y2);
    } else {
        float* yr = (float*)outv + (size_t)r * D_MODEL;
        yr[t] = y0; yr[t+256] = y1; yr[t+512] = y2;
    }
}

// --------------------------------------------- weight convert+transpose to bf16
template<int MODE>
__global__ __launch_bounds__(256) void convw_kernel(
    const float* __restrict__ W, __hip_bfloat16* __restrict__ BT,
    int K, int N, size_t in_stride, size_t out_stride)
{
    __shared__ __hip_bfloat16 sT[64][72];
    W  += (size_t)blockIdx.z * in_stride;
    BT += (size_t)blockIdx.z * out_stride;
    int k0 = blockIdx.x * 64, n0 = blockIdx.y * 64;
    int t = threadIdx.x;
    int kl = t >> 4, nl4 = (t & 15) * 4;
    #pragma unroll
    for (int i = 0; i < 4; i++) {
        int k = k0 + kl + i * 16;
        int n = n0 + nl4;
        const float* src = (MODE == 0) ? (W + (size_t)k * N + n)
                                       : (W + ((size_t)(n >> 6) * K + k) * 64 + (n & 63));
        float4 v = *(const float4*)src;
        sT[nl4 + 0][kl + i*16] = __float2bfloat16(v.x);
        sT[nl4 + 1][kl + i*16] = __float2bfloat16(v.y);
        sT[nl4 + 2][kl + i*16] = __float2bfloat16(v.z);
        sT[nl4 + 3][kl + i*16] = __float2bfloat16(v.w);
    }
    __syncthreads();
    int nl = t >> 2, seg = (t & 3) * 16;
    uint4* dst = (uint4*)(BT + (size_t)(n0 + nl) * K + k0 + seg);
    dst[0] = *(uint4*)&sT[nl][seg];
    dst[1] = *(uint4*)&sT[nl][seg + 8];
}

// ---------------------------------------------------------------- bf16 MFMA GEMM
// T4 counted-vmcnt pipeline: 3 LDS buffers, 2-deep prefetch, raw s_barrier, vmcnt
// never drained to 0 in steady state (m218: counted vs drain0 = +38-73%).
// Per iteration: vmcnt(4) [stage t done, t+1 in flight] -> barrier -> ds_read frags
// -> lgkmcnt(0) [reads landed] -> barrier [all waves done reading -> oldest buffer
// reusable] -> STAGE(t+2) -> MFMA. Last iter waits vmcnt(0).
// OMODE: 0 = f32 out (+bias,+res)   1 = QKV bf16 scatter   2 = bf16 out
//        3 = split-K over blockIdx.z, atomicAdd f32 into C (C pre-holds residual;
//            bias added by z==0 slice only; relu unsupported)
template<int OMODE>
__global__ __launch_bounds__(256, 3) void gemm128(
    const __hip_bfloat16* __restrict__ A, const __hip_bfloat16* __restrict__ BT,
    const float* __restrict__ bias, const float* __restrict__ res,
    void* __restrict__ Cv, int M, int N, int K, int relu)
{
    __shared__ short sA[3][128 * 32];
    __shared__ short sB[3][128 * 32];
    int t = threadIdx.x;
    int wave = t >> 6, lane = t & 63;
    int l16 = lane & 15, quad = (lane >> 4) & 3;
    int wm = wave >> 1, wn = wave & 1;
    int bm = blockIdx.x * 128, bn = blockIdx.y * 128;

    int kbeg = 0, kend = K;
    if (OMODE == 3) { int KS = K >> 1; kbeg = blockIdx.z * KS; kend = kbeg + KS; }
    int nsteps = (kend - kbeg) >> 5;

    int u = lane >> 2;
    int skey = ((u & 3) ^ ((u >> 2) & 3));
    int sseg = (lane & 3) ^ skey;
    int c0 = wave * 2, c1 = wave * 2 + 1;
    int rA0 = c0 * 16 + u, rA1 = c1 * 16 + u;
    int fkey = ((l16 & 3) ^ ((l16 >> 2) & 3));

    const f32x4 zf = {0.f, 0.f, 0.f, 0.f};
    f32x4 acc[4][4];
    #pragma unroll
    for (int mi = 0; mi < 4; mi++)
        #pragma unroll
        for (int ni = 0; ni < 4; ni++) acc[mi][ni] = zf;

    const __hip_bfloat16* pA0 = A  + (size_t)(bm + rA0) * K + kbeg + sseg * 8;
    const __hip_bfloat16* pA1 = A  + (size_t)(bm + rA1) * K + kbeg + sseg * 8;
    const __hip_bfloat16* pB0 = BT + (size_t)(bn + rA0) * K + kbeg + sseg * 8;
    const __hip_bfloat16* pB1 = BT + (size_t)(bn + rA1) * K + kbeg + sseg * 8;

    #define STAGE(bufi, kk) do { \
        gld16(pA0 + (kk), &sA[bufi][c0 * 512]); \
        gld16(pA1 + (kk), &sA[bufi][c1 * 512]); \
        gld16(pB0 + (kk), &sB[bufi][c0 * 512]); \
        gld16(pB1 + (kk), &sB[bufi][c1 * 512]); \
    } while (0)

    STAGE(0, 0);
    if (nsteps > 1) STAGE(1, 32);

    int bufr = 0, bufs = 2;
    for (int it = 0; it < nsteps; ++it) {
        // wait for tile 'it' staging (own loads); keep stage t+1 in flight
        if (it + 1 < nsteps) { asm volatile("s_waitcnt vmcnt(4)" ::: "memory"); }
        else                 { asm volatile("s_waitcnt vmcnt(0)" ::: "memory"); }
        __builtin_amdgcn_sched_barrier(0);
        __builtin_amdgcn_s_barrier();           // all waves staged buf[it%3]
        __builtin_amdgcn_sched_barrier(0);

        const short* curA = &sA[bufr][0];
        const short* curB = &sB[bufr][0];
        bf16x8 aF[4], bF[4];
        #pragma unroll
        for (int mi = 0; mi < 4; mi++)
            aF[mi] = *(const bf16x8*)&curA[(wm * 64 + mi * 16 + l16) * 32 + ((quad ^ fkey) * 8)];
        #pragma unroll
        for (int ni = 0; ni < 4; ni++)
            bF[ni] = *(const bf16x8*)&curB[(wn * 64 + ni * 16 + l16) * 32 + ((quad ^ fkey) * 8)];

        asm volatile("s_waitcnt lgkmcnt(0)" ::: "memory");   // frags in regs NOW
        __builtin_amdgcn_sched_barrier(0);
        __builtin_amdgcn_s_barrier();           // all waves done reading -> oldest buf free
        __builtin_amdgcn_sched_barrier(0);

        if (it + 2 < nsteps) STAGE(bufs, (it + 2) * 32);   // 2-ahead prefetch

        #pragma unroll
        for (int ni = 0; ni < 4; ni++)
            #pragma unroll
            for (int mi = 0; mi < 4; mi++)
                acc[mi][ni] = __builtin_amdgcn_mfma_f32_16x16x32_bf16(aF[mi], bF[ni], acc[mi][ni], 0, 0, 0);

        bufr = (bufr == 2) ? 0 : bufr + 1;
        bufs = (bufs == 2) ? 0 : bufs + 1;
    }
    #undef STAGE

    #pragma unroll
    for (int mi = 0; mi < 4; mi++) {
        #pragma unroll
        for (int ni = 0; ni < 4; ni++) {
            int row0 = bm + wm * 64 + mi * 16 + quad * 4;
            int col  = bn + wn * 64 + ni * 16 + l16;
            #pragma unroll
            for (int r = 0; r < 4; r++) {
                int row = row0 + r;
                float v = acc[mi][ni][r];
                if (OMODE == 3) {
                    float* C = (float*)Cv;
                    if (blockIdx.z == 0 && bias) v += bias[col];
                    unsafeAtomicAdd(&C[(size_t)row * N + col], v);
                    continue;
                }
                if (OMODE != 1 && bias) v += bias[col];
                if (relu) v = fmaxf(v, 0.f);
                if (OMODE == 0) {
                    float* C = (float*)Cv;
                    if (res) v += res[(size_t)row * N + col];
                    C[(size_t)row * N + col] = v;
                } else if (OMODE == 1) {
                    int which = col / D_MODEL, cc = col % D_MODEL;
                    int bb = row >> 10, ss = row & 1023, hh = cc >> 6, e = cc & 63;
                    ((__hip_bfloat16*)Cv)[(size_t)which * MROWS * D_MODEL +
                        (((size_t)(bb * NHEAD + hh)) * SEQ + ss) * HS + e] = __float2bfloat16(v);
                } else {
                    ((__hip_bfloat16*)Cv)[(size_t)row * N + col] = __float2bfloat16(v);
                }
            }
        }
    }
    (void)M;
}

// ---------------------------------------------------------------- V transpose: (bh,s,e) -> (bh,e,s)
__global__ __launch_bounds__(256) void vtrans_kernel(
    const __hip_bfloat16* __restrict__ vb, __hip_bfloat16* __restrict__ vt)
{
    __shared__ short tile[64][66];
    int bh = blockIdx.x, st = blockIdx.y;
    const short* src = (const short*)vb + ((size_t)bh * SEQ + st * 64) * HS;
    int t = threadIdx.x;
    #pragma unroll
    for (int i = 0; i < 2; i++) {
        int slot = t + i * 256;
        int row = slot >> 3, seg = slot & 7;
        *(uint4*)&tile[row][seg * 8] = *(const uint4*)(src + row * HS + seg * 8);
    }
    __syncthreads();
    short* dst = (short*)vt + (size_t)bh * HS * SEQ + st * 64;
    #pragma unroll
    for (int i = 0; i < 2; i++) {
        int slot = t + i * 256;
        int e = slot >> 3, seg = slot & 7;
        union { uint4 u; short s[8]; } pk;
        #pragma unroll
        for (int j = 0; j < 8; j++) pk.s[j] = tile[seg * 8 + j][e];
        *(uint4*)(dst + (size_t)e * SEQ + seg * 8) = pk.u;
    }
}

// ---------------------------------------------------------------- MFMA flash attention v3 (S^T orientation)
// Block = 2 waves = 128 queries of one (b,h); wave owns 64 queries (4 qt-tiles).
// XCD-bijective blockIdx remap (K/VT L2-local) + double-buffered sK/sVT prefetch.
__global__ __launch_bounds__(128, 2) void attn_mfma_kernel(
    const __hip_bfloat16* __restrict__ q, const __hip_bfloat16* __restrict__ k,
    const __hip_bfloat16* __restrict__ v, const int* __restrict__ mask,
    __hip_bfloat16* __restrict__ ao)
{
    __shared__ short sK[2][64 * 64];
    __shared__ short sVT[2][64 * 64];
    __shared__ short sP[2][64 * 64];
    __shared__ float mskf[SEQ];
    int bid = blockIdx.x;
    int xcd = bid & 7, j = bid >> 3;
    int bh  = ((j >> 3) << 3) | xcd;
    int qt8 = j & 7;
    int b = bh / NHEAD, hh = bh % NHEAD;
    int t = threadIdx.x, w = t >> 6, lane = t & 63;
    int l16 = lane & 15, quad = lane >> 4;
    const float scale = 0.036084391824351615f;  // 768^-0.5
    const f32x4 zf = {0.f, 0.f, 0.f, 0.f};

    #pragma unroll
    for (int i = 0; i < 8; i++) {
        int idx = t + i * 128;
        mskf[idx] = mask[b * SEQ + idx] ? 0.f : -1e30f;
    }

    // Q B-frags: lane n=query(l16), k=dim s*32+quad*8..+7
    int qb0 = qt8 * 128 + w * 64;
    const __hip_bfloat16* qbase = q + ((size_t)bh * SEQ + qb0) * HS;
    bf16x8 qf[4][2];
    #pragma unroll
    for (int qt = 0; qt < 4; qt++)
        #pragma unroll
        for (int s = 0; s < 2; s++)
            qf[qt][s] = *(const bf16x8*)(qbase + (qt * 16 + l16) * HS + s * 32 + quad * 8);

    f32x4 accO[4][4];            // [dt][qt]: O^T tile, row=dim dt*16+quad*4+r, col=query qt*16+l16
    float m_st[4], l_st[4];      // per qt (query qt*16+l16)
    #pragma unroll
    for (int dt = 0; dt < 4; dt++)
        #pragma unroll
        for (int qt = 0; qt < 4; qt++) accO[dt][qt] = zf;
    #pragma unroll
    for (int qt = 0; qt < 4; qt++) { m_st[qt] = -1e30f; l_st[qt] = 0.f; }

    // staging geometry
    int rowL = lane >> 3;
    int sgl = ((lane & 7) ^ ((lane >> 3) & 7)) * 8;   // swizzled global seg (shorts)
    const __hip_bfloat16* kg0 = k + ((size_t)bh * SEQ) * HS;
    const __hip_bfloat16* vtg0 = v + (size_t)bh * HS * SEQ;   // v = pre-transposed vT here
    short* myP = &sP[w][0];

    // prologue: stage K-tile 0 into buffer 0
    #pragma unroll
    for (int i = 0; i < 4; i++) {
        int c = w * 4 + i;
        int rr = c * 8 + rowL;
        gld16(kg0  + (size_t)rr * HS  + sgl, (char*)&sK[0][0]  + c * 1024);
        gld16(vtg0 + (size_t)rr * SEQ + sgl, (char*)&sVT[0][0] + c * 1024);
    }
    __syncthreads();

    int buf = 0;
    for (int kc = 0; kc < 16; kc++) {
        // prefetch next K-tile into the other buffer (in flight during compute)
        if (kc < 15) {
            const __hip_bfloat16* kg  = kg0  + (size_t)(kc + 1) * 64 * HS;
            const __hip_bfloat16* vtg = vtg0 + (kc + 1) * 64;
            #pragma unroll
            for (int i = 0; i < 4; i++) {
                int c = w * 4 + i;
                int rr = c * 8 + rowL;
                gld16(kg  + (size_t)rr * HS  + sgl, (char*)&sK[buf ^ 1][0]  + c * 1024);
                gld16(vtg + (size_t)rr * SEQ + sgl, (char*)&sVT[buf ^ 1][0] + c * 1024);
            }
        }
        short* cK  = &sK[buf][0];
        short* cVT = &sVT[buf][0];

        // all sK/sVT reads up front
        bf16x8 vf[4][2];
        #pragma unroll
        for (int dt = 0; dt < 4; dt++)
            #pragma unroll
            for (int s = 0; s < 2; s++)
                vf[dt][s] = *(bf16x8*)&cVT[(dt * 16 + l16) * 64 + (((s * 4 + quad) ^ (l16 & 7)) * 8)];
        f32x4 sc[4][4];   // [kt][qt]
        #pragma unroll
        for (int kt = 0; kt < 4; kt++) {
            bf16x8 kf0 = *(bf16x8*)&cK[(kt * 16 + l16) * 64 + ((quad ^ (l16 & 7)) * 8)];
            bf16x8 kf1 = *(bf16x8*)&cK[(kt * 16 + l16) * 64 + (((4 + quad) ^ (l16 & 7)) * 8)];
            #pragma unroll
            for (int qt = 0; qt < 4; qt++) {
                f32x4 c = __builtin_amdgcn_mfma_f32_16x16x32_bf16(kf0, qf[qt][0], zf, 0, 0, 0);
                sc[kt][qt] = __builtin_amdgcn_mfma_f32_16x16x32_bf16(kf1, qf[qt][1], c, 0, 0, 0);
            }
        }
        // scale + mask (mask indexed by key row)
        #pragma unroll
        for (int kt = 0; kt < 4; kt++) {
            f32x4 mk = *(f32x4*)&mskf[kc * 64 + kt * 16 + quad * 4];
            #pragma unroll
            for (int qt = 0; qt < 4; qt++)
                #pragma unroll
                for (int r = 0; r < 4; r++)
                    sc[kt][qt][r] = sc[kt][qt][r] * scale + mk[r];
        }
        // online softmax per query column
        #pragma unroll
        for (int qt = 0; qt < 4; qt++) {
            float rm = -1e30f;
            #pragma unroll
            for (int kt = 0; kt < 4; kt++)
                #pragma unroll
                for (int r = 0; r < 4; r++) rm = fmaxf(rm, sc[kt][qt][r]);
            rm = fmaxf(rm, __shfl_xor(rm, 16));
            rm = fmaxf(rm, __shfl_xor(rm, 32));
            float mnew = fmaxf(m_st[qt], rm);
            float corr = __expf(m_st[qt] - mnew);
            m_st[qt] = mnew;
            float ps = 0.f;
            #pragma unroll
            for (int kt = 0; kt < 4; kt++) {
                union { uint2 u; short s[4]; } pk;
                #pragma unroll
                for (int r = 0; r < 4; r++) {
                    float p = __expf(sc[kt][qt][r] - mnew);
                    ps += p;
                    pk.s[r] = f2bf_s(p);
                }
                // P[query][key], keys kt*16+quad*4..+3; seg swizzle on query row bits
                *(uint2*)&myP[(qt * 16 + l16) * 64 +
                              (((kt * 2 + (quad >> 1)) ^ (l16 & 7)) * 8) + (quad & 1) * 4] = pk.u;
            }
            ps += __shfl_xor(ps, 16);
            ps += __shfl_xor(ps, 32);
            l_st[qt] = l_st[qt] * corr + ps;
            #pragma unroll
            for (int dt = 0; dt < 4; dt++) accO[dt][qt] *= corr;
        }
        asm volatile("" ::: "memory");   // keep pf reads after P writes (same-wave DS is in-order)
        // PV: O^T += V^T @ P^T  (B-frag = P rows)
        #pragma unroll
        for (int qt = 0; qt < 4; qt++) {
            bf16x8 pf0 = *(bf16x8*)&myP[(qt * 16 + l16) * 64 + ((quad ^ (l16 & 7)) * 8)];
            bf16x8 pf1 = *(bf16x8*)&myP[(qt * 16 + l16) * 64 + (((4 + quad) ^ (l16 & 7)) * 8)];
            #pragma unroll
            for (int dt = 0; dt < 4; dt++) {
                accO[dt][qt] = __builtin_amdgcn_mfma_f32_16x16x32_bf16(vf[dt][0], pf0, accO[dt][qt], 0, 0, 0);
                accO[dt][qt] = __builtin_amdgcn_mfma_f32_16x16x32_bf16(vf[dt][1], pf1, accO[dt][qt], 0, 0, 0);
            }
        }
        __syncthreads();   // drains prefetch (had full compute phase to land); next buffer ready
        buf ^= 1;
    }

    // epilogue: O = O^T / l, pack 4 consecutive dims per b64 store
    #pragma unroll
    for (int qt = 0; qt < 4; qt++) {
        float inv = 1.f / l_st[qt];
        int row = qb0 + qt * 16 + l16;
        __hip_bfloat16* orow = ao + ((size_t)(b * SEQ + row)) * D_MODEL + hh * HS;
        #pragma unroll
        for (int dt = 0; dt < 4; dt++) {
            union { uint2 u; short s[4]; } pk;
            #pragma unroll
            for (int r = 0; r < 4; r++) pk.s[r] = f2bf_s(accO[dt][qt][r] * inv);
            *(uint2*)(orow + dt * 16 + quad * 4) = pk.u;
        }
    }
}

// ---------------------------------------------------------------- head FC1: (8,768)@(768,3072)+relu
__global__ __launch_bounds__(256) void fc1_kernel(
    const float* __restrict__ A, const float* __restrict__ W,
    const float* __restrict__ bias, float* __restrict__ out)
{
    __shared__ float sa[D_MODEL];
    int row = blockIdx.x, t = threadIdx.x;
    for (int i = t; i < D_MODEL; i += 256) sa[i] = A[(size_t)row * D_MODEL + i];
    __syncthreads();
    int col = blockIdx.y * 256 + t;
    float s = 0.f;
    #pragma unroll 8
    for (int kk = 0; kk < D_MODEL; kk++) s = fmaf(sa[kk], W[(size_t)kk * DFF + col], s);
    s += bias[col];
    out[(size_t)row * DFF + col] = fmaxf(s, 0.f);
}

// ---------------------------------------------------------------- head FC2: (8,3072)@(3072,16)
__global__ __launch_bounds__(256) void fc2_kernel(
    const float* __restrict__ A, const float* __restrict__ W,
    const float* __restrict__ bias, float* __restrict__ out)
{
    __shared__ float wred[4][NCLS];
    int row = blockIdx.x, t = threadIdx.x;
    int wave = t >> 6, lane = t & 63;
    const float* a = A + (size_t)row * DFF;
    float acc[NCLS];
    #pragma unroll
    for (int c = 0; c < NCLS; c++) acc[c] = 0.f;
    for (int kk = t; kk < DFF; kk += 256) {
        float av = a[kk];
        const float4* wr = (const float4*)(W + (size_t)kk * NCLS);
        float4 w0 = wr[0], w1 = wr[1], w2 = wr[2], w3 = wr[3];
        acc[0]  = fmaf(av, w0.x, acc[0]);  acc[1]  = fmaf(av, w0.y, acc[1]);
        acc[2]  = fmaf(av, w0.z, acc[2]);  acc[3]  = fmaf(av, w0.w, acc[3]);
        acc[4]  = fmaf(av, w1.x, acc[4]);  acc[5]  = fmaf(av, w1.y, acc[5]);
        acc[6]  = fmaf(av, w1.z, acc[6]);  acc[7]  = fmaf(av, w1.w, acc[7]);
        acc[8]  = fmaf(av, w2.x, acc[8]);  acc[9]  = fmaf(av, w2.y, acc[9]);
        acc[10] = fmaf(av, w2.z, acc[10]); acc[11] = fmaf(av, w2.w, acc[11]);
        acc[12] = fmaf(av, w3.x, acc[12]); acc[13] = fmaf(av, w3.y, acc[13]);
        acc[14] = fmaf(av, w3.z, acc[14]); acc[15] = fmaf(av, w3.w, acc[15]);
    }
    #pragma unroll
    for (int c = 0; c < NCLS; c++)
        #pragma unroll
        for (int off = 32; off; off >>= 1) acc[c] += __shfl_down(acc[c], off);
    if (lane == 0)
        #pragma unroll
        for (int c = 0; c < NCLS; c++) wred[wave][c] = acc[c];
    __syncthreads();
    if (t < NCLS)
        out[row * NCLS + t] = wred[0][t] + wred[1][t] + wred[2][t] + wred[3][t] + bias[t];
}

// ---------------------------------------------------------------- launch
extern "C" void kernel_launch(void* const* d_in, const int* in_sizes, int n_in,
                              void* d_out, int out_size, void* d_ws, size_t ws_size,
                              hipStream_t stream)
{
    const int*   x     = (const int*)  d_in[0];
    const int*   amask = (const int*)  d_in[1];
    const float* tok   = (const float*)d_in[2];
    const float* pos   = (const float*)d_in[3];
    const float* Wq    = (const float*)d_in[4];
    const float* Wk    = (const float*)d_in[5];
    const float* Wv    = (const float*)d_in[6];
    const float* Wo    = (const float*)d_in[7];
    const float* bo    = (const float*)d_in[8];
    const float* ln1w  = (const float*)d_in[9];
    const float* ln1b  = (const float*)d_in[10];
    const float* ln2w  = (const float*)d_in[11];
    const float* ln2b  = (const float*)d_in[12];
    const float* W1    = (const float*)d_in[13];
    const float* b1    = (const float*)d_in[14];
    const float* W2    = (const float*)d_in[15];
    const float* b2    = (const float*)d_in[16];
    const float* lnfw  = (const float*)d_in[17];
    const float* lnfb  = (const float*)d_in[18];
    const float* cW1   = (const float*)d_in[19];
    const float* cb1   = (const float*)d_in[20];
    const float* cW2   = (const float*)d_in[21];
    const float* cb2   = (const float*)d_in[22];

    char* base = (char*)d_ws;
    const size_t MD = (size_t)MROWS * D_MODEL;
    float* h = (float*)base;                         base += MD * 4;
    __hip_bfloat16* xn = (__hip_bfloat16*)base;      base += MD * 2;
    __hip_bfloat16* qb = (__hip_bfloat16*)base;      base += MD * 2;
    __hip_bfloat16* kb = (__hip_bfloat16*)base;      base += MD * 2;
    __hip_bfloat16* vb = (__hip_bfloat16*)base;      base += MD * 2;
    __hip_bfloat16* vT = (__hip_bfloat16*)base;      base += MD * 2;
    __hip_bfloat16* ff = (__hip_bfloat16*)base;      base += (size_t)MROWS * DFF * 2;
    float* lnf = (float*)base;                       base += (size_t)NB * D_MODEL * 4;
    float* cls = (float*)base;                       base += (size_t)NB * DFF * 4;
    __hip_bfloat16* wQKV = (__hip_bfloat16*)base;    base += (size_t)NLAYER * 3 * D_MODEL * D_MODEL * 2;
    __hip_bfloat16* wTo = (__hip_bfloat16*)base;     base += (size_t)NLAYER * D_MODEL * D_MODEL * 2;
    __hip_bfloat16* wT1 = (__hip_bfloat16*)base;     base += (size_t)NLAYER * D_MODEL * DFF * 2;
    __hip_bfloat16* wT2 = (__hip_bfloat16*)base;     base += (size_t)NLAYER * DFF * D_MODEL * 2;

    const size_t SQW = (size_t)D_MODEL * D_MODEL;
    const size_t SFF = (size_t)D_MODEL * DFF;

    convw_kernel<1><<<dim3(12,12,4), 256, 0, stream>>>(Wq, wQKV + 0 * SQW, D_MODEL, D_MODEL, SQW, 3 * SQW);
    convw_kernel<1><<<dim3(12,12,4), 256, 0, stream>>>(Wk, wQKV + 1 * SQW, D_MODEL, D_MODEL, SQW, 3 * SQW);
    convw_kernel<1><<<dim3(12,12,4), 256, 0, stream>>>(Wv, wQKV + 2 * SQW, D_MODEL, D_MODEL, SQW, 3 * SQW);
    convw_kernel<0><<<dim3(12,12,4), 256, 0, stream>>>(Wo, wTo, D_MODEL, D_MODEL, SQW, SQW);
    convw_kernel<0><<<dim3(12,48,4), 256, 0, stream>>>(W1, wT1, D_MODEL, DFF, SFF, SFF);
    convw_kernel<0><<<dim3(48,12,4), 256, 0, stream>>>(W2, wT2, DFF, D_MODEL, SFF, SFF);

    embed_kernel<<<MROWS, 256, 0, stream>>>(x, tok, pos, h);

    dim3 gQKV(MROWS / 128, (3 * D_MODEL) / 128);
    dim3 gDS(MROWS / 128, D_MODEL / 128, 2);   // split-K=2
    dim3 gF(MROWS / 128, DFF / 128);
    for (int l = 0; l < NLAYER; l++) {
        ln_kernel<1><<<MROWS, 256, 0, stream>>>(h, ln1w + l * D_MODEL, ln1b + l * D_MODEL, xn, 1, 0);
        gemm128<1><<<gQKV, 256, 0, stream>>>(xn, wQKV + l * 3 * SQW, nullptr, nullptr, qb, MROWS, 3 * D_MODEL, D_MODEL, 0);
        vtrans_kernel<<<dim3(NB * NHEAD, SEQ / 64), 256, 0, stream>>>(vb, vT);
        attn_mfma_kernel<<<NB * NHEAD * 8, 128, 0, stream>>>(qb, kb, vT, amask, xn);
        gemm128<3><<<gDS, 256, 0, stream>>>(xn, wTo + l * SQW, bo + l * D_MODEL, nullptr, h, MROWS, D_MODEL, D_MODEL, 0);
        ln_kernel<1><<<MROWS, 256, 0, stream>>>(h, ln2w + l * D_MODEL, ln2b + l * D_MODEL, xn, 1, 0);
        gemm128<2><<<gF, 256, 0, stream>>>(xn, wT1 + l * SFF, b1 + l * DFF, nullptr, ff, MROWS, DFF, D_MODEL, 1);
        gemm128<3><<<gDS, 256, 0, stream>>>(ff, wT2 + l * SFF, b2 + l * D_MODEL, nullptr, h, MROWS, D_MODEL, DFF, 0);
    }
    ln_kernel<0><<<NB, 256, 0, stream>>>(h, lnfw, lnfb, lnf, SEQ, SEQ - 1);
    fc1_kernel<<<dim3(NB, DFF / 256), 256, 0, stream>>>(lnf, cW1, cb1, cls);
    fc2_kernel<<<NB, 256, 0, stream>>>(cls, cW2, cb2, (float*)d_out);
}